// Round 7
// baseline (207.614 us; speedup 1.0000x reference)
//
#include <hip/hip_runtime.h>
#include <math.h>

#define BB 4
#define CC 64
#define HH 128
#define WW 128
#define OO 64
#define HWW (HH * WW)

#define TPIX  64            // pixels per tile (one 64-wide row segment)
#define WROWS 5
#define WCOLS 68            // TPIX + 4 halo
#define NPOS  (WROWS * WCOLS)   // 340
#define XSTR  36            // [pos][ch] channel-row stride (32 + 4 pad)

typedef short bf8 __attribute__((ext_vector_type(8)));
typedef float f32x4 __attribute__((ext_vector_type(4)));

// ws byte offsets (weight fragments only, ~216 KB)
#define WHF_OFF  0          // main W hi frags: 18*4*64*8 shorts = 73728 B
#define WLF_OFF  73728      // main W lo frags
#define WOMH_OFF 147456     // om W hi frags: 18*2*64*8 shorts = 36864 B
#define WOML_OFF 184320     // om W lo frags

__device__ inline unsigned short f2bf(float f) {           // RNE (prep only)
    union { float f; unsigned u; } x; x.f = f;
    unsigned u = x.u;
    return (unsigned short)((u + 0x7FFFu + ((u >> 16) & 1u)) >> 16);
}
__device__ inline float bf2f(unsigned short h) {
    union { unsigned u; float f; } x; x.u = ((unsigned)h) << 16;
    return x.f;
}
// pack truncated-bf16 of (a,b): lo16 = bf(a), hi16 = bf(b)
__device__ inline unsigned pack_hi2(float a, float b) {
    return (__float_as_uint(a) >> 16) | (__float_as_uint(b) & 0xFFFF0000u);
}

// ---------------------------------------------------------------------------
// prep: weights -> bf16 hi/lo A-fragments (RNE split).
// chunk ch = half*9 + tap covers channels [half*32, half*32+32) of tap.
// A-frag: lane l holds W[o = grp*16 + (l&15)][k = (l>>4)*8 + j].
__global__ void prep_kernel(const float* __restrict__ weight,     // (O,C,3,3)
                            const float* __restrict__ om_weight,  // (27,C,3,3)
                            unsigned short* __restrict__ whf,
                            unsigned short* __restrict__ wlf,
                            unsigned short* __restrict__ womh,
                            unsigned short* __restrict__ woml)
{
    int d = blockIdx.x * 256 + threadIdx.x;
    if (d < 18 * 4 * 64 * 8) {
        int j  = d & 7;
        int l  = (d >> 3) & 63;
        int og = (d >> 9) & 3;
        int ch = d >> 11;
        int o  = og * 16 + (l & 15);
        int kk = (l >> 4) * 8 + j;
        int c  = (ch / 9) * 32 + kk;
        int tap = ch % 9;
        float w = weight[(o * CC + c) * 9 + tap];
        unsigned short h = f2bf(w);
        whf[d] = h;
        wlf[d] = f2bf(w - bf2f(h));
    }
    int d2 = d - 18 * 4 * 64 * 8;
    if (d2 >= 0 && d2 < 18 * 2 * 64 * 8) {
        int j  = d2 & 7;
        int l  = (d2 >> 3) & 63;
        int og = (d2 >> 9) & 1;
        int ch = d2 >> 10;
        int o  = og * 16 + (l & 15);
        int kk = (l >> 4) * 8 + j;
        int c  = (ch / 9) * 32 + kk;
        int tap = ch % 9;
        float w = (o < 27) ? om_weight[(o * CC + c) * 9 + tap] : 0.f;
        unsigned short h = f2bf(w);
        womh[d2] = h;
        woml[d2] = f2bf(w - bf2f(h));
    }
}

// ---------------------------------------------------------------------------
// Fused kernel. Block = 64-pixel row segment, 256 threads = 4 waves.
// Wave w owns N-subtile w (16 pixels) and ALL 64 outputs -> B-frags built
// in-register from the LDS window; no barriers inside om/main loops.
// Window layout Xs[pos][ch] (stride 36 floats): zero-filled out-of-image halo.
__global__ void __launch_bounds__(256, 2)
fused_kernel(const float* __restrict__ x,     // (B,C,H,W)
             const unsigned short* __restrict__ whf,
             const unsigned short* __restrict__ wlf,
             const unsigned short* __restrict__ womh,
             const unsigned short* __restrict__ woml,
             const float* __restrict__ bias,
             const float* __restrict__ om_bias,
             float* __restrict__ out)         // (B,O,H,W)
{
    __shared__ __align__(16) float  Xs[NPOS * XSTR];   // 48,960 B
    __shared__ __align__(16) float4 swt4[9 * TPIX];    //  9,216 B
    __shared__ int   sidx[9 * TPIX];                   //  2,304 B
    __shared__ float omL[27 * TPIX];                   //  6,912 B  => 67,392 B

    int t    = threadIdx.x;
    int lane = t & 63;
    int wv   = __builtin_amdgcn_readfirstlane(t >> 6);

    int bid = blockIdx.x;           // b*256 + ho*2 + q
    int b   = bid >> 8;
    int r   = bid & 255;
    int ho  = r >> 1;
    int w0  = (r & 1) << 6;

    int pixl = (lane & 15);         // pixel within subtile
    int pix  = wv * 16 + pixl;      // pixel within tile
    int ch0  = (lane >> 4) * 8;     // this lane's 8-channel octet (B-frag k)

    // ---------------- stage: x half-window -> LDS [pos][ch], zero halo -----
    auto stage = [&](int half) {
        const float* xh = x + ((size_t)(b * CC + half * 32)) * HWW;
#pragma unroll 1
        for (int i = t; i < NPOS * 32; i += 256) {     // 10880 elems
            int c   = i / NPOS;
            int pos = i - c * NPOS;
            int rr  = pos / WCOLS;
            int cc2 = pos - rr * WCOLS;
            int gy = ho - 2 + rr, gx = w0 - 2 + cc2;
            bool ok = (gy >= 0) & (gy < HH) & (gx >= 0) & (gx < WW);
            float v = ok ? xh[(size_t)c * HWW + gy * WW + gx] : 0.f;
            Xs[pos * XSTR + c] = v;
        }
    };

    // ---------------- om conv: barrier-free, B in-register -----------------
    f32x4 accom[2];
    accom[0] = (f32x4){0.f, 0.f, 0.f, 0.f};
    accom[1] = (f32x4){0.f, 0.f, 0.f, 0.f};
    auto om_pass = [&](int half) {
#pragma unroll 1
        for (int tap = 0; tap < 9; tap++) {
            int ch = half * 9 + tap;
            int ky = tap / 3, kx = tap - ky * 3;
            int pos = (ky + 1) * WCOLS + pix + kx + 1;
            const float* Xp = &Xs[pos * XSTR + ch0];
            float4 f0 = *(const float4*)(Xp);
            float4 f1 = *(const float4*)(Xp + 4);
            bf8 bh;
            ((unsigned*)&bh)[0] = pack_hi2(f0.x, f0.y);
            ((unsigned*)&bh)[1] = pack_hi2(f0.z, f0.w);
            ((unsigned*)&bh)[2] = pack_hi2(f1.x, f1.y);
            ((unsigned*)&bh)[3] = pack_hi2(f1.z, f1.w);
#pragma unroll
            for (int og = 0; og < 2; og++) {
                const bf8 ah = *(const bf8*)&womh[((size_t)(ch * 2 + og) * 64 + lane) * 8];
                const bf8 al = *(const bf8*)&woml[((size_t)(ch * 2 + og) * 64 + lane) * 8];
                accom[og] = __builtin_amdgcn_mfma_f32_16x16x32_bf16(ah, bh, accom[og], 0, 0, 0);
                accom[og] = __builtin_amdgcn_mfma_f32_16x16x32_bf16(al, bh, accom[og], 0, 0, 0);
            }
        }
    };

    // ---------------- main conv: barrier-free, B in-register ---------------
    f32x4 acc[4];
#pragma unroll
    for (int og = 0; og < 4; og++) acc[og] = (f32x4){0.f, 0.f, 0.f, 0.f};

    auto main_pass = [&](int half) {
        const float* xg = x + ((size_t)(b * CC + half * 32 + ch0)) * HWW;
#pragma unroll 1
        for (int tap = 0; tap < 9; tap++) {
            int ch = half * 9 + tap;
            int it = tap * TPIX + pix;
            float4 w4 = swt4[it];
            int sv = sidx[it];
            int y0 = ((sv >> 16) & 0x7FFF) - 16;
            int x0 = (sv & 0xFFFF) - 16;

            float v[8];
            if (sv >= 0) {
                int base = ((y0 - ho + 2) * WCOLS + (x0 - w0 + 2)) * XSTR + ch0;
                const float* Xp = &Xs[base];
                float4 c00a = *(const float4*)(Xp);
                float4 c00b = *(const float4*)(Xp + 4);
                float4 c01a = *(const float4*)(Xp + XSTR);
                float4 c01b = *(const float4*)(Xp + XSTR + 4);
                float4 c10a = *(const float4*)(Xp + WCOLS * XSTR);
                float4 c10b = *(const float4*)(Xp + WCOLS * XSTR + 4);
                float4 c11a = *(const float4*)(Xp + (WCOLS + 1) * XSTR);
                float4 c11b = *(const float4*)(Xp + (WCOLS + 1) * XSTR + 4);
                v[0] = w4.x * c00a.x + w4.y * c01a.x + w4.z * c10a.x + w4.w * c11a.x;
                v[1] = w4.x * c00a.y + w4.y * c01a.y + w4.z * c10a.y + w4.w * c11a.y;
                v[2] = w4.x * c00a.z + w4.y * c01a.z + w4.z * c10a.z + w4.w * c11a.z;
                v[3] = w4.x * c00a.w + w4.y * c01a.w + w4.z * c10a.w + w4.w * c11a.w;
                v[4] = w4.x * c00b.x + w4.y * c01b.x + w4.z * c10b.x + w4.w * c11b.x;
                v[5] = w4.x * c00b.y + w4.y * c01b.y + w4.z * c10b.y + w4.w * c11b.y;
                v[6] = w4.x * c00b.z + w4.y * c01b.z + w4.z * c10b.z + w4.w * c11b.z;
                v[7] = w4.x * c00b.w + w4.y * c01b.w + w4.z * c10b.w + w4.w * c11b.w;
            } else {
                // rare escape: clamped global gather
                int cy0 = min(max(y0, 0), HH - 1), cy1 = min(max(y0 + 1, 0), HH - 1);
                int cx0 = min(max(x0, 0), WW - 1), cx1 = min(max(x0 + 1, 0), WW - 1);
                int i00 = cy0 * WW + cx0, i01 = cy0 * WW + cx1;
                int i10 = cy1 * WW + cx0, i11 = cy1 * WW + cx1;
#pragma unroll
                for (int j = 0; j < 8; j++) {
                    const float* xc = xg + (size_t)j * HWW;
                    v[j] = w4.x * xc[i00] + w4.y * xc[i01]
                         + w4.z * xc[i10] + w4.w * xc[i11];
                }
            }
            // truncation hi/lo split
            bf8 bh, bl;
#pragma unroll
            for (int k2 = 0; k2 < 4; k2++) {
                float a = v[2 * k2], bb = v[2 * k2 + 1];
                unsigned ua = __float_as_uint(a), ub = __float_as_uint(bb);
                unsigned ha = ua & 0xFFFF0000u, hb = ub & 0xFFFF0000u;
                float ra = a - __uint_as_float(ha);
                float rb = bb - __uint_as_float(hb);
                ((unsigned*)&bh)[k2] = (ua >> 16) | hb;
                ((unsigned*)&bl)[k2] = pack_hi2(ra, rb);
            }
#pragma unroll
            for (int og = 0; og < 4; og++) {
                const bf8 ah = *(const bf8*)&whf[((size_t)(ch * 4 + og) * 64 + lane) * 8];
                const bf8 al = *(const bf8*)&wlf[((size_t)(ch * 4 + og) * 64 + lane) * 8];
                acc[og] = __builtin_amdgcn_mfma_f32_16x16x32_bf16(ah, bh, acc[og], 0, 0, 0);
                acc[og] = __builtin_amdgcn_mfma_f32_16x16x32_bf16(ah, bl, acc[og], 0, 0, 0);
                acc[og] = __builtin_amdgcn_mfma_f32_16x16x32_bf16(al, bh, acc[og], 0, 0, 0);
            }
        }
    };

    // =========================== block timeline ===========================
    stage(1);
    __syncthreads();
    om_pass(1);
    __syncthreads();          // Xs(half1) reads done before restage
    stage(0);
    __syncthreads();
    om_pass(0);               // Xs now holds half 0 (kept for main_pass(0))

    // om epilogue -> omL
    {
#pragma unroll
        for (int og = 0; og < 2; og++) {
#pragma unroll
            for (int rg = 0; rg < 4; rg++) {
                int m = og * 16 + (lane >> 4) * 4 + rg;
                if (m < 27) {
                    float v = accom[og][rg] + om_bias[m];
                    if (m >= 18) v = 1.f / (1.f + expf(-v));
                    omL[m * TPIX + pix] = v;
                }
            }
        }
    }
    __syncthreads();

    // phase B: sampling params per (tap, pixel)
#pragma unroll 1
    for (int it = t; it < 9 * TPIX; it += 256) {
        int k  = it >> 6;
        int pp = it & 63;
        float oy = omL[k * TPIX + pp];
        float ox = omL[(9 + k) * TPIX + pp];
        float mm = omL[(18 + k) * TPIX + pp];
        int ky = k / 3, kx = k - ky * 3;
        float py = oy + (float)(ho + ky - 1);
        float px = ox + (float)(w0 + pp + kx - 1);
        float fy = floorf(py), fx = floorf(px);
        float ly = py - fy, lx = px - fx;
        int y0 = (int)fy, x0 = (int)fx;
        bool vy0 = (y0 >= 0) & (y0 < HH);
        bool vy1 = (y0 + 1 >= 0) & (y0 + 1 < HH);
        bool vx0 = (x0 >= 0) & (x0 < WW);
        bool vx1 = (x0 + 1 >= 0) & (x0 + 1 < WW);
        float4 w4;
        w4.x = (vy0 & vx0) ? (1.f - ly) * (1.f - lx) * mm : 0.f;
        w4.y = (vy0 & vx1) ? (1.f - ly) * lx * mm : 0.f;
        w4.z = (vy1 & vx0) ? ly * (1.f - lx) * mm : 0.f;
        w4.w = (vy1 & vx1) ? ly * lx * mm : 0.f;
        swt4[it] = w4;
        bool inw = (y0 >= ho - 2) & (y0 <= ho + 1) & (x0 >= w0 - 2) & (x0 <= w0 + 64);
        int y0c = min(max(y0, -8), 135);
        int x0c = min(max(x0, -8), 135);
        sidx[it] = ((y0c + 16) << 16) | ((x0c + 16) & 0xFFFF)
                 | (inw ? 0 : (int)0x80000000);
    }
    __syncthreads();

    main_pass(0);             // Xs holds half 0
    __syncthreads();          // all Xs reads done before restage
    stage(1);
    __syncthreads();
    main_pass(1);

    // epilogue: C/D col=lane&15 (pixel), row=(lane>>4)*4+rg (o within og*16)
    int prow = ho * WW + w0;
#pragma unroll
    for (int og = 0; og < 4; og++) {
#pragma unroll
        for (int rg = 0; rg < 4; rg++) {
            int o = og * 16 + (lane >> 4) * 4 + rg;
            out[((size_t)(b * OO + o)) * HWW + prow + pix] = acc[og][rg] + bias[o];
        }
    }
}

// ---------------------------------------------------------------------------
extern "C" void kernel_launch(void* const* d_in, const int* in_sizes, int n_in,
                              void* d_out, int out_size, void* d_ws, size_t ws_size,
                              hipStream_t stream)
{
    (void)in_sizes; (void)n_in; (void)out_size; (void)ws_size;
    const float* x      = (const float*)d_in[0];
    const float* weight = (const float*)d_in[1];
    const float* bias   = (const float*)d_in[2];
    const float* om_w   = (const float*)d_in[3];
    const float* om_b   = (const float*)d_in[4];
    float* out = (float*)d_out;
    char*  ws  = (char*)d_ws;

    unsigned short* whf  = (unsigned short*)(ws + WHF_OFF);
    unsigned short* wlf  = (unsigned short*)(ws + WLF_OFF);
    unsigned short* womh = (unsigned short*)(ws + WOMH_OFF);
    unsigned short* woml = (unsigned short*)(ws + WOML_OFF);

    int prep_n = 18 * 4 * 64 * 8 + 18 * 2 * 64 * 8;  // 55296
    prep_kernel<<<(prep_n + 255) / 256, 256, 0, stream>>>(weight, om_w, whf, wlf, womh, woml);

    int nblk = BB * HH * (WW / TPIX);  // 1024
    fused_kernel<<<nblk, 256, 0, stream>>>(x, whf, wlf, womh, woml, bias, om_b, out);
}

// Round 8
// 127.264 us; speedup vs baseline: 1.6314x; 1.6314x over previous
//
#include <hip/hip_runtime.h>
#include <hip/hip_bf16.h>
#include <math.h>

#define BB 4
#define CC 64
#define HH 128
#define WW 128
#define OO 64
#define HWW (HH * WW)

typedef short bf8 __attribute__((ext_vector_type(8)));
typedef float f32x4 __attribute__((ext_vector_type(4)));

// ws byte offsets (weight fragments only, ~216 KB)
#define WHF_OFF  0          // main W hi frags: 18*4*64*8 shorts = 73728 B
#define WLF_OFF  73728      // main W lo frags
#define WOMH_OFF 147456     // om W hi frags: 18*2*64*8 shorts = 36864 B
#define WOML_OFF 184320     // om W lo frags

__device__ inline unsigned short f2bf(float f) {           // RNE (prep only)
    union { float f; unsigned u; } x; x.f = f;
    unsigned u = x.u;
    return (unsigned short)((u + 0x7FFFu + ((u >> 16) & 1u)) >> 16);
}
__device__ inline float bf2f(unsigned short h) {
    union { unsigned u; float f; } x; x.u = ((unsigned)h) << 16;
    return x.f;
}
// RNE-pack two floats to bf16x2 (low16 = bf(a), high16 = bf(b))
__device__ inline unsigned pack_rne2(float a, float b) {
    __hip_bfloat162 h2 = __float22bfloat162_rn(make_float2(a, b));
    union { __hip_bfloat162 h; unsigned u; } cv; cv.h = h2;
    return cv.u;
}

// ---------------------------------------------------------------------------
// prep: weights -> bf16 hi/lo A-fragments (RNE split).
// chunk ch = half*9 + tap covers channels [half*32, half*32+32) of tap.
// A-frag: lane l holds W[o = grp*16 + (l&15)][k = (l>>4)*8 + j].
__global__ void prep_kernel(const float* __restrict__ weight,     // (O,C,3,3)
                            const float* __restrict__ om_weight,  // (27,C,3,3)
                            unsigned short* __restrict__ whf,
                            unsigned short* __restrict__ wlf,
                            unsigned short* __restrict__ womh,
                            unsigned short* __restrict__ woml)
{
    int d = blockIdx.x * 256 + threadIdx.x;
    if (d < 18 * 4 * 64 * 8) {
        int j  = d & 7;
        int l  = (d >> 3) & 63;
        int wv = (d >> 9) & 3;
        int ch = d >> 11;
        int o  = wv * 16 + (l & 15);
        int kk = (l >> 4) * 8 + j;
        int c  = (ch / 9) * 32 + kk;
        int tap = ch % 9;
        float w = weight[(o * CC + c) * 9 + tap];
        unsigned short h = f2bf(w);
        whf[d] = h;
        wlf[d] = f2bf(w - bf2f(h));
    }
    int d2 = d - 18 * 4 * 64 * 8;
    if (d2 >= 0 && d2 < 18 * 2 * 64 * 8) {
        int j  = d2 & 7;
        int l  = (d2 >> 3) & 63;
        int og = (d2 >> 9) & 1;
        int ch = d2 >> 10;
        int o  = og * 16 + (l & 15);
        int kk = (l >> 4) * 8 + j;
        int c  = (ch / 9) * 32 + kk;
        int tap = ch % 9;
        float w = (o < 27) ? om_weight[(o * CC + c) * 9 + tap] : 0.f;
        unsigned short h = f2bf(w);
        womh[d2] = h;
        woml[d2] = f2bf(w - bf2f(h));
    }
}

// ---------------------------------------------------------------------------
// Fused kernel (round-6 structure: 32-pixel tiles, per-tap frag exchange,
// 1 barrier/tap, 4 blocks/CU). This round: single RNE-bf16 B for V
// (W stays hi/lo), RNE packing via v_cvt_pk_bf16_f32.
__global__ void __launch_bounds__(256, 4)
fused_kernel(const float* __restrict__ x,     // (B,C,H,W)
             const unsigned short* __restrict__ whf,
             const unsigned short* __restrict__ wlf,
             const unsigned short* __restrict__ womh,
             const unsigned short* __restrict__ woml,
             const float* __restrict__ bias,
             const float* __restrict__ om_bias,
             float* __restrict__ out)         // (B,O,H,W)
{
    __shared__ __align__(16) float Xs2[8 * 180 * 4];   // [cg][pos][j] 23,040 B
    __shared__ __align__(16) unsigned vhf[2][32][21];  // 5,376 B (pad 21: conflict-free)
    __shared__ float swt[4][288];                      // 4,608 B
    __shared__ int   sidx[288];                        // 1,152 B  -> total 34,176 B

    int t    = threadIdx.x;
    int lane = t & 63;
    int wv   = t >> 6;

    int bid = blockIdx.x;           // b*512 + ho*4 + q
    int b   = bid >> 9;
    int r   = bid & 511;
    int ho  = r >> 2;
    int w0  = (r & 3) << 5;

    // ---------------- stage: x half-window -> LDS (zero halo) --------------
    auto stage = [&](int half) {
        const float* xh = x + ((size_t)(b * CC + half * 32)) * HWW;
#pragma unroll 1
        for (int i = t; i < 1440; i += 256) {          // cg*180 + pos
            int cg  = i / 180;
            int pos = i - cg * 180;
            int rr  = pos / 36;
            int cc2 = pos - rr * 36;
            int gy = ho - 2 + rr, gx = w0 - 2 + cc2;
            bool ok = (gy >= 0) & (gy < HH) & (gx >= 0) & (gx < WW);
            int gi = ok ? gy * WW + gx : 0;
            const float* xc = xh + (size_t)cg * 4 * HWW + gi;
            float4 v;
            v.x = xc[0]; v.y = xc[HWW]; v.z = xc[2 * HWW]; v.w = xc[3 * HWW];
            if (!ok) { v.x = 0.f; v.y = 0.f; v.z = 0.f; v.w = 0.f; }
            *(float4*)&Xs2[(cg * 180 + pos) * 4] = v;
        }
    };

    // ---------------- om conv: single RNE-bf16 B, W hi/lo (2 MFMAs/tap) ----
    f32x4 accom = (f32x4){0.f, 0.f, 0.f, 0.f};
    auto om_pass = [&](int half) {
        int og = wv & 1;
        int s  = wv >> 1;
        int pix_s = s * 16 + (lane & 15);
        int cg0   = (lane >> 4) * 2;      // channels cg0*4 .. cg0*4+7
#pragma unroll 1
        for (int tap = 0; tap < 9; tap++) {
            int ch = half * 9 + tap;
            int ky = tap / 3, kx = tap - ky * 3;
            int pos = (ky + 1) * 36 + pix_s + kx + 1;
            float4 f0 = *(const float4*)&Xs2[(cg0 * 180 + pos) * 4];
            float4 f1 = *(const float4*)&Xs2[((cg0 + 1) * 180 + pos) * 4];
            bf8 bh;
            ((unsigned*)&bh)[0] = pack_rne2(f0.x, f0.y);
            ((unsigned*)&bh)[1] = pack_rne2(f0.z, f0.w);
            ((unsigned*)&bh)[2] = pack_rne2(f1.x, f1.y);
            ((unsigned*)&bh)[3] = pack_rne2(f1.z, f1.w);
            const bf8 ah = *(const bf8*)&womh[((size_t)(ch * 2 + og) * 64 + lane) * 8];
            const bf8 al = *(const bf8*)&woml[((size_t)(ch * 2 + og) * 64 + lane) * 8];
            accom = __builtin_amdgcn_mfma_f32_16x16x32_bf16(ah, bh, accom, 0, 0, 0);
            accom = __builtin_amdgcn_mfma_f32_16x16x32_bf16(al, bh, accom, 0, 0, 0);
        }
    };

    // ---------------- main conv half-pass ----------------
    f32x4 acc[2];
    acc[0] = (f32x4){0.f, 0.f, 0.f, 0.f};
    acc[1] = (f32x4){0.f, 0.f, 0.f, 0.f};

    auto main_pass = [&](int half) {
        int pix = t & 31;
        int cg  = t >> 5;               // 0..7, 4 channels each
        const float* xg = x + ((size_t)(b * CC + half * 32 + cg * 4)) * HWW;
#pragma unroll 1
        for (int tap = 0; tap < 9; tap++) {
            int ach  = half * 9 + tap;
            int buf  = tap & 1;
            int item = tap * 32 + pix;
            float w00 = swt[0][item], w01 = swt[1][item];
            float w10 = swt[2][item], w11 = swt[3][item];
            int sv = sidx[item];
            int y0 = ((sv >> 16) & 0x7FFF) - 16;
            int x0 = (sv & 0xFFFF) - 16;
            const bf8 ah = *(const bf8*)&whf[((size_t)(ach * 4 + wv) * 64 + lane) * 8];
            const bf8 al = *(const bf8*)&wlf[((size_t)(ach * 4 + wv) * 64 + lane) * 8];

            float v0, v1, v2, v3;
            if (sv >= 0) {
                int o00 = (y0 - ho + 2) * 36 + (x0 - w0 + 2);
                const float* Xp = &Xs2[(cg * 180 + o00) * 4];
                float4 c00 = *(const float4*)(Xp);
                float4 c01 = *(const float4*)(Xp + 4);
                float4 c10 = *(const float4*)(Xp + 144);
                float4 c11 = *(const float4*)(Xp + 148);
                v0 = w00 * c00.x + w01 * c01.x + w10 * c10.x + w11 * c11.x;
                v1 = w00 * c00.y + w01 * c01.y + w10 * c10.y + w11 * c11.y;
                v2 = w00 * c00.z + w01 * c01.z + w10 * c10.z + w11 * c11.z;
                v3 = w00 * c00.w + w01 * c01.w + w10 * c10.w + w11 * c11.w;
            } else {
                int cy0 = min(max(y0, 0), HH - 1), cy1 = min(max(y0 + 1, 0), HH - 1);
                int cx0 = min(max(x0, 0), WW - 1), cx1 = min(max(x0 + 1, 0), WW - 1);
                int i00 = cy0 * WW + cx0, i01 = cy0 * WW + cx1;
                int i10 = cy1 * WW + cx0, i11 = cy1 * WW + cx1;
                const float* x0p = xg;
                const float* x1p = xg + HWW;
                const float* x2p = xg + 2 * HWW;
                const float* x3p = xg + 3 * HWW;
                v0 = w00 * x0p[i00] + w01 * x0p[i01] + w10 * x0p[i10] + w11 * x0p[i11];
                v1 = w00 * x1p[i00] + w01 * x1p[i01] + w10 * x1p[i10] + w11 * x1p[i11];
                v2 = w00 * x2p[i00] + w01 * x2p[i01] + w10 * x2p[i10] + w11 * x2p[i11];
                v3 = w00 * x3p[i00] + w01 * x3p[i01] + w10 * x3p[i10] + w11 * x3p[i11];
            }
            // single RNE-bf16 V
            uint2 hw;
            hw.x = pack_rne2(v0, v1);
            hw.y = pack_rne2(v2, v3);
            *(uint2*)&vhf[buf][pix][cg * 2] = hw;
            __syncthreads();
#pragma unroll
            for (int s2 = 0; s2 < 2; s2++) {
                const bf8 bv = *(const bf8*)&vhf[buf][s2 * 16 + (lane & 15)][(lane >> 4) * 4];
                acc[s2] = __builtin_amdgcn_mfma_f32_16x16x32_bf16(ah, bv, acc[s2], 0, 0, 0);
                acc[s2] = __builtin_amdgcn_mfma_f32_16x16x32_bf16(al, bv, acc[s2], 0, 0, 0);
            }
        }
    };

    // =========================== block timeline ===========================
    stage(1);
    __syncthreads();
    om_pass(1);
    __syncthreads();          // Xs2(half1) reads done before restage
    stage(0);
    __syncthreads();
    om_pass(0);               // Xs2 now holds half 0 (kept for main_pass(0))

    // om epilogue -> omL (union with vhf region; unused until main loop)
    float* omL = (float*)&vhf[0][0][0];   // 27*32 floats = 3,456 B < 10,752 B
    {
        int og = wv & 1, s = wv >> 1;
#pragma unroll
        for (int rg = 0; rg < 4; rg++) {
            int m = og * 16 + (lane >> 4) * 4 + rg;
            if (m < 27) {
                int pp = s * 16 + (lane & 15);
                float v = accom[rg] + om_bias[m];
                if (m >= 18) v = 1.f / (1.f + expf(-v));
                omL[m * 32 + pp] = v;
            }
        }
    }
    __syncthreads();

    // phase B: sampling params per (tap, pixel)
#pragma unroll 1
    for (int it = t; it < 288; it += 256) {
        int k  = it >> 5;
        int pp = it & 31;
        float oy = omL[k * 32 + pp];
        float ox = omL[(9 + k) * 32 + pp];
        float mm = omL[(18 + k) * 32 + pp];
        int ky = k / 3, kx = k - ky * 3;
        float py = oy + (float)(ho + ky - 1);
        float px = ox + (float)(w0 + pp + kx - 1);
        float fy = floorf(py), fx = floorf(px);
        float ly = py - fy, lx = px - fx;
        int y0 = (int)fy, x0 = (int)fx;
        bool vy0 = (y0 >= 0) & (y0 < HH);
        bool vy1 = (y0 + 1 >= 0) & (y0 + 1 < HH);
        bool vx0 = (x0 >= 0) & (x0 < WW);
        bool vx1 = (x0 + 1 >= 0) & (x0 + 1 < WW);
        swt[0][it] = (vy0 & vx0) ? (1.f - ly) * (1.f - lx) * mm : 0.f;
        swt[1][it] = (vy0 & vx1) ? (1.f - ly) * lx * mm : 0.f;
        swt[2][it] = (vy1 & vx0) ? ly * (1.f - lx) * mm : 0.f;
        swt[3][it] = (vy1 & vx1) ? ly * lx * mm : 0.f;
        bool inw = (y0 >= ho - 2) & (y0 <= ho + 1) & (x0 >= w0 - 2) & (x0 <= w0 + 32);
        int y0c = min(max(y0, -8), 135);
        int x0c = min(max(x0, -8), 135);
        sidx[it] = ((y0c + 16) << 16) | ((x0c + 16) & 0xFFFF)
                 | (inw ? 0 : (int)0x80000000);
    }
    __syncthreads();

    main_pass(0);             // Xs2 holds half 0
    stage(1);                 // safe: in-loop tap-8 barrier orders Xs2 reads
    __syncthreads();
    main_pass(1);

    // epilogue
    int prow = ho * WW + w0;
#pragma unroll
    for (int s = 0; s < 2; s++) {
#pragma unroll
        for (int rg = 0; rg < 4; rg++) {
            int o  = wv * 16 + (lane >> 4) * 4 + rg;
            int pp = s * 16 + (lane & 15);
            out[((size_t)(b * OO + o)) * HWW + prow + pp] = acc[s][rg] + bias[o];
        }
    }
}

// ---------------------------------------------------------------------------
extern "C" void kernel_launch(void* const* d_in, const int* in_sizes, int n_in,
                              void* d_out, int out_size, void* d_ws, size_t ws_size,
                              hipStream_t stream)
{
    (void)in_sizes; (void)n_in; (void)out_size; (void)ws_size;
    const float* x      = (const float*)d_in[0];
    const float* weight = (const float*)d_in[1];
    const float* bias   = (const float*)d_in[2];
    const float* om_w   = (const float*)d_in[3];
    const float* om_b   = (const float*)d_in[4];
    float* out = (float*)d_out;
    char*  ws  = (char*)d_ws;

    unsigned short* whf  = (unsigned short*)(ws + WHF_OFF);
    unsigned short* wlf  = (unsigned short*)(ws + WLF_OFF);
    unsigned short* womh = (unsigned short*)(ws + WOMH_OFF);
    unsigned short* woml = (unsigned short*)(ws + WOML_OFF);

    int prep_n = 18 * 4 * 64 * 8 + 18 * 2 * 64 * 8;  // 55296
    prep_kernel<<<(prep_n + 255) / 256, 256, 0, stream>>>(weight, om_w, whf, wlf, womh, woml);

    int nblk = BB * HH * (WW / 32);  // 2048
    fused_kernel<<<nblk, 256, 0, stream>>>(x, whf, wlf, womh, woml, bias, om_b, out);
}